// Round 1
// baseline (265.854 us; speedup 1.0000x reference)
//
#include <hip/hip_runtime.h>
#include <hip/hip_bf16.h>

// CausalSelfAttention: B=4 T=2048 H=1024 NH=16 HD=64, fp32 I/O, bf16 MFMA internal.
// Pipeline: cvt(X,Wq,Wk,Wv)->bf16 ; fused QKV NT-GEMM (m97-style 128x128x32) writing
// Q(scaled by 0.125*log2e),K as [bh][t][d] and V transposed [bh][d][t] ; flash attn
// (QBLK=64, KBLK=64, 4 waves, online softmax in exp2 domain, causal tile-skip).
// Workspace use: 70 MB.

typedef float  f32x4 __attribute__((ext_vector_type(4)));
typedef short  s16x8 __attribute__((ext_vector_type(8)));

#define LOG2E 1.44269504088896340736f

__device__ __forceinline__ unsigned short f2bf(float f) {
  unsigned u = __float_as_uint(f);
  u += 0x7FFFu + ((u >> 16) & 1u);   // RNE to bf16 (inputs finite)
  return (unsigned short)(u >> 16);
}

__device__ __forceinline__ float ex2(float x) {
#if __has_builtin(__builtin_amdgcn_exp2f)
  return __builtin_amdgcn_exp2f(x);
#else
  return exp2f(x);
#endif
}
__device__ __forceinline__ float rcp_(float x) {
#if __has_builtin(__builtin_amdgcn_rcpf)
  return __builtin_amdgcn_rcpf(x);
#else
  return 1.0f / x;
#endif
}

#define GLOAD16(gp, lp)                                                          \
  __builtin_amdgcn_global_load_lds(                                              \
      (const __attribute__((address_space(1))) void*)(gp),                       \
      (__attribute__((address_space(3))) void*)(lp), 16, 0, 0)

#define MFMA(a, b, c) __builtin_amdgcn_mfma_f32_16x16x32_bf16((a), (b), (c), 0, 0, 0)

// ---------------------------------------------------------------- fp32 -> bf16
__global__ __launch_bounds__(256) void cvt_bf16(const float* __restrict__ s,
                                                unsigned short* __restrict__ d) {
  size_t i = (size_t)blockIdx.x * 256 + threadIdx.x;  // 8 elems/thread, exact grid
  const float4* sp = (const float4*)s + i * 2;
  float4 a = sp[0], b = sp[1];
  s16x8 r;
  r[0] = f2bf(a.x); r[1] = f2bf(a.y); r[2] = f2bf(a.z); r[3] = f2bf(a.w);
  r[4] = f2bf(b.x); r[5] = f2bf(b.y); r[6] = f2bf(b.z); r[7] = f2bf(b.w);
  *(s16x8*)(d + i * 8) = r;
}

// ------------------------------------------------------------------- QKV GEMM
// out[m][n] = sum_k X[m][k]*W[n][k] + b[n]; m=b*2048+t, n=h*64+d.
// which=0 -> Q (scaled 0.125*log2e) [bh][t][d]; 1 -> K [bh][t][d]; 2 -> V^T [bh][d][t]
__global__ __launch_bounds__(256) void qkv_gemm(
    const unsigned short* __restrict__ Xb,
    const unsigned short* __restrict__ Wqb, const unsigned short* __restrict__ Wkb,
    const unsigned short* __restrict__ Wvb,
    const float* __restrict__ bq, const float* __restrict__ bk,
    const float* __restrict__ bv,
    unsigned short* __restrict__ Qo, unsigned short* __restrict__ Ko,
    unsigned short* __restrict__ Vto) {
  int bid0 = blockIdx.x;
  int bid  = (bid0 & 7) * 192 + (bid0 >> 3);  // XCD swizzle (1536 = 8*192, bijective)
  int which = bid >> 9;
  int rt = bid & 511;
  int mt = rt >> 3, ntl = rt & 7;
  const unsigned short* W = (which == 0) ? Wqb : (which == 1) ? Wkb : Wvb;
  const float* bias = (which == 0) ? bq : (which == 1) ? bk : bv;

  __shared__ __align__(16) unsigned short As[128 * 32];  // [m-row][k] 64B rows
  __shared__ __align__(16) unsigned short Bs[128 * 32];  // [n-row][k]

  int tid = threadIdx.x;
  int lane = tid & 63, wid = tid >> 6;
  int q16 = lane & 15, g = lane >> 4;
  int wr = wid >> 1, wc = wid & 1;

  int arow = tid >> 2;              // staging slot row (tid*16B, 64B rows)
  int ainner = (tid & 3) << 4;      // byte within row
  const char* Ag = (const char*)Xb + ((size_t)(mt * 128 + arow) * 1024) * 2 + ainner;
  const char* Bg = (const char*)W + ((size_t)(ntl * 128 + arow) * 1024) * 2 + ainner;
  char* Al = (char*)As + tid * 16;
  char* Bl = (char*)Bs + tid * 16;

  f32x4 acc[4][4] = {};

  for (int kb = 0; kb < 1024; kb += 32) {
    GLOAD16(Ag + kb * 2, Al);
    GLOAD16(Ag + kb * 2 + 64 * 2048, Al + 4096);
    GLOAD16(Bg + kb * 2, Bl);
    GLOAD16(Bg + kb * 2 + 64 * 2048, Bl + 4096);
    __syncthreads();
    s16x8 af[4], bf[4];
#pragma unroll
    for (int mi = 0; mi < 4; ++mi)
      af[mi] = *(const s16x8*)((const char*)As + (wr * 64 + mi * 16 + q16) * 64 + g * 16);
#pragma unroll
    for (int ni = 0; ni < 4; ++ni)
      bf[ni] = *(const s16x8*)((const char*)Bs + (wc * 64 + ni * 16 + q16) * 64 + g * 16);
#pragma unroll
    for (int mi = 0; mi < 4; ++mi)
#pragma unroll
      for (int ni = 0; ni < 4; ++ni)
        acc[mi][ni] = MFMA(af[mi], bf[ni], acc[mi][ni]);
    __syncthreads();
  }

  float qsc = (which == 0) ? (0.125f * LOG2E) : 1.0f;
  unsigned short* Out = (which == 0) ? Qo : (which == 1) ? Ko : Vto;
#pragma unroll
  for (int ni = 0; ni < 4; ++ni) {
    int n = ntl * 128 + wc * 64 + ni * 16 + q16;
    float bvl = bias[n];
    int h = n >> 6, d = n & 63;
#pragma unroll
    for (int mi = 0; mi < 4; ++mi) {
      int m0 = mt * 128 + wr * 64 + mi * 16 + g * 4;
#pragma unroll
      for (int j = 0; j < 4; ++j) {
        int m = m0 + j;
        int bb = m >> 11, t = m & 2047;
        float v = (acc[mi][ni][j] + bvl) * qsc;
        size_t addr;
        if (which == 2) addr = ((size_t)(bb * 16 + h) * 64 + d) * 2048 + t;
        else            addr = ((size_t)(bb * 16 + h) * 2048 + t) * 64 + d;
        Out[addr] = f2bf(v);
      }
    }
  }
}

// ------------------------------------------------------------- flash attention
// grid 2048 = 64 bh * 32 q-tiles. Block: 4 waves, each owns 16 q-rows.
// K_lds/Vt_lds staged via global_load_lds with pre-swizzled SOURCE (XOR (row&7)<<4)
// so b128 fragment reads are bank-conflict-free (linear 128B rows would be 16-way).
__global__ __launch_bounds__(256) void attn_fwd(
    const unsigned short* __restrict__ Qw, const unsigned short* __restrict__ Kw,
    const unsigned short* __restrict__ Vtw, const float* __restrict__ maskp,
    float* __restrict__ out) {
  int bid0 = blockIdx.x;
  int bid = (bid0 & 7) * 256 + (bid0 >> 3);  // XCD swizzle: each XCD gets 8 whole bh
  int bh = bid >> 5, qt = bid & 31;
  int qb = qt << 6;
  int tid = threadIdx.x;
  int lane = tid & 63, wid = tid >> 6;
  int q16 = lane & 15, g = lane >> 4;
  int bidx = bh >> 4;  // batch

  __shared__ __align__(16) char Ks[8192];      // [k 64][128B], swizzled
  __shared__ __align__(16) char Vs[8192];      // V^T: [d 64][128B k], swizzled
  __shared__ __align__(16) char Ps[4][2304];   // per-wave P: [q 16][stride 144B]

  size_t qrow = (size_t)bh * 2048 + qb + wid * 16 + q16;
  s16x8 qa0 = *(const s16x8*)(Qw + qrow * 64 + g * 8);        // d 0..31 chunk
  s16x8 qa1 = *(const s16x8*)(Qw + qrow * 64 + 32 + g * 8);   // d 32..63

  float m_r[4], l_r[4];
  f32x4 o[4] = {};
#pragma unroll
  for (int r = 0; r < 4; ++r) { m_r[r] = -1e30f; l_r[r] = 0.f; }

  int srow = tid >> 3;               // staging row (128B rows, 2 rows/thread: +32)
  int sinner = (tid & 7) << 4;
  int ssw = sinner ^ ((srow & 7) << 4);
  const char* Kg = (const char*)Kw + ((size_t)bh * 2048 + srow) * 128 + ssw;
  const char* Vg = (const char*)Vtw + ((size_t)bh * 64 + srow) * 4096 + ssw;
  char* Kl = Ks + tid * 16;
  char* Vl = Vs + tid * 16;
  char* pw = Ps[wid];

  int ntile = qt + 1;
  int qg0 = qb + wid * 16 + g * 4;

  for (int kt = 0; kt < ntile; ++kt) {
    int kb = kt << 6;
    GLOAD16(Kg + (size_t)kb * 128, Kl);
    GLOAD16(Kg + (size_t)kb * 128 + 4096, Kl + 4096);
    GLOAD16(Vg + kb * 2, Vl);
    GLOAD16(Vg + kb * 2 + 131072, Vl + 4096);
    __syncthreads();

    float x[4][4];
#pragma unroll
    for (int t4 = 0; t4 < 4; ++t4) {
      int kk = t4 * 16 + q16;
      const char* kr = Ks + kk * 128;
      int sw = (kk & 7) << 4;
      s16x8 kf0 = *(const s16x8*)(kr + ((g * 16) ^ sw));
      s16x8 kf1 = *(const s16x8*)(kr + ((64 + g * 16) ^ sw));
      f32x4 s = {0.f, 0.f, 0.f, 0.f};
      s = MFMA(qa0, kf0, s);
      s = MFMA(qa1, kf1, s);
      int kcol = kb + kk;
      float mv = maskp[(bidx << 11) + kcol] * LOG2E;  // mask already in scores units
#pragma unroll
      for (int r = 0; r < 4; ++r) {
        float xv = s[r] + mv;                 // s already includes 0.125*log2e via Q
        if (kcol > qg0 + r) xv = -1e30f;      // causal
        x[t4][r] = xv;
      }
    }

#pragma unroll
    for (int r = 0; r < 4; ++r) {
      float rm = fmaxf(fmaxf(x[0][r], x[1][r]), fmaxf(x[2][r], x[3][r]));
      rm = fmaxf(rm, __shfl_xor(rm, 1));
      rm = fmaxf(rm, __shfl_xor(rm, 2));
      rm = fmaxf(rm, __shfl_xor(rm, 4));
      rm = fmaxf(rm, __shfl_xor(rm, 8));
      float mn = fmaxf(m_r[r], rm);
      float sc = ex2(m_r[r] - mn);
      m_r[r] = mn;
      l_r[r] *= sc;
      o[0][r] *= sc; o[1][r] *= sc; o[2][r] *= sc; o[3][r] *= sc;
      float p0 = ex2(x[0][r] - mn), p1 = ex2(x[1][r] - mn);
      float p2 = ex2(x[2][r] - mn), p3 = ex2(x[3][r] - mn);
      x[0][r] = p0; x[1][r] = p1; x[2][r] = p2; x[3][r] = p3;
      float rs = (p0 + p1) + (p2 + p3);
      rs += __shfl_xor(rs, 1);
      rs += __shfl_xor(rs, 2);
      rs += __shfl_xor(rs, 4);
      rs += __shfl_xor(rs, 8);
      l_r[r] += rs;
    }

    // P: C-layout (row=4g+r, col=16t4+q16) -> LDS -> A-layout frags
#pragma unroll
    for (int t4 = 0; t4 < 4; ++t4)
#pragma unroll
      for (int r = 0; r < 4; ++r)
        *(unsigned short*)(pw + (g * 4 + r) * 144 + (t4 * 16 + q16) * 2) = f2bf(x[t4][r]);
    asm volatile("" ::: "memory");  // order b16 writes vs b128 reads (same wave, in-order DS)
    s16x8 pa0 = *(const s16x8*)(pw + q16 * 144 + g * 16);
    s16x8 pa1 = *(const s16x8*)(pw + q16 * 144 + 64 + g * 16);
#pragma unroll
    for (int dt = 0; dt < 4; ++dt) {
      int d = dt * 16 + q16;
      const char* vr = Vs + d * 128;
      int sw = (q16 & 7) << 4;
      s16x8 v0 = *(const s16x8*)(vr + ((g * 16) ^ sw));
      s16x8 v1 = *(const s16x8*)(vr + ((64 + g * 16) ^ sw));
      o[dt] = MFMA(pa0, v0, o[dt]);
      o[dt] = MFMA(pa1, v1, o[dt]);
    }
    __syncthreads();
  }

  size_t ob = ((size_t)bh * 2048 + qb + wid * 16 + g * 4) * 64 + q16;
#pragma unroll
  for (int r = 0; r < 4; ++r) {
    float inv = rcp_(l_r[r]);
#pragma unroll
    for (int dt = 0; dt < 4; ++dt)
      out[ob + (size_t)r * 64 + dt * 16] = o[dt][r] * inv;
  }
}

// ------------------------------------------------------------------- launcher
extern "C" void kernel_launch(void* const* d_in, const int* in_sizes, int n_in,
                              void* d_out, int out_size, void* d_ws, size_t ws_size,
                              hipStream_t stream) {
  const float* hs   = (const float*)d_in[0];
  const float* mask = (const float*)d_in[1];
  const float* Wq   = (const float*)d_in[2];
  const float* bq   = (const float*)d_in[3];
  const float* Wk   = (const float*)d_in[4];
  const float* bk   = (const float*)d_in[5];
  const float* Wv   = (const float*)d_in[6];
  const float* bv   = (const float*)d_in[7];
  float* out = (float*)d_out;

  char* w = (char*)d_ws;  // 70 MB total
  unsigned short* Xb  = (unsigned short*)w; w += (size_t)8192 * 1024 * 2;
  unsigned short* Wqb = (unsigned short*)w; w += (size_t)1024 * 1024 * 2;
  unsigned short* Wkb = (unsigned short*)w; w += (size_t)1024 * 1024 * 2;
  unsigned short* Wvb = (unsigned short*)w; w += (size_t)1024 * 1024 * 2;
  unsigned short* Qw  = (unsigned short*)w; w += (size_t)8192 * 1024 * 2;
  unsigned short* Kw  = (unsigned short*)w; w += (size_t)8192 * 1024 * 2;
  unsigned short* Vtw = (unsigned short*)w; w += (size_t)8192 * 1024 * 2;

  cvt_bf16<<<4096, 256, 0, stream>>>(hs, Xb);   // 8.4M elems
  cvt_bf16<<<512, 256, 0, stream>>>(Wq, Wqb);   // 1M each
  cvt_bf16<<<512, 256, 0, stream>>>(Wk, Wkb);
  cvt_bf16<<<512, 256, 0, stream>>>(Wv, Wvb);
  qkv_gemm<<<1536, 256, 0, stream>>>(Xb, Wqb, Wkb, Wvb, bq, bk, bv, Qw, Kw, Vtw);
  attn_fwd<<<2048, 256, 0, stream>>>(Qw, Kw, Vtw, mask, out);
}

// Round 2
// 182.474 us; speedup vs baseline: 1.4569x; 1.4569x over previous
//
#include <hip/hip_runtime.h>
#include <hip/hip_bf16.h>

// CausalSelfAttention: B=4 T=2048 H=1024 NH=16 HD=64, fp32 I/O, bf16 MFMA internal.
// cvt(X,W*)->bf16 ; fused QKV NT-GEMM (m97-style 128x128x32) writing Q(pre-scaled by
// 0.125*log2e), K as [bh][t][d], V^T as [bh][d][t] ; flash attn: swapped QK^T
// (P[k][q] lane-local), no-max exp2 softmax, normalizer via ones-fragment MFMA,
// P kept fully in registers (permuted K-row order -> B-fragment slot order),
// double-buffered K/V staging with counted vmcnt(4).

typedef float  f32x4 __attribute__((ext_vector_type(4)));
typedef short  s16x8 __attribute__((ext_vector_type(8)));
typedef unsigned short u16;

#define LOG2E 1.44269504088896340736f

__device__ __forceinline__ u16 f2bf(float f) {
  unsigned u = __float_as_uint(f);
  u += 0x7FFFu + ((u >> 16) & 1u);   // RNE (inputs finite)
  return (u16)(u >> 16);
}

__device__ __forceinline__ float ex2(float x) {
#if __has_builtin(__builtin_amdgcn_exp2f)
  return __builtin_amdgcn_exp2f(x);
#else
  return exp2f(x);
#endif
}
__device__ __forceinline__ float rcp_(float x) {
#if __has_builtin(__builtin_amdgcn_rcpf)
  return __builtin_amdgcn_rcpf(x);
#else
  return 1.0f / x;
#endif
}
__device__ __forceinline__ unsigned cvtpk(float lo, float hi) {
  unsigned r;
  asm("v_cvt_pk_bf16_f32 %0, %1, %2" : "=v"(r) : "v"(lo), "v"(hi));
  return r;
}

#define GLOAD16(gp, lp)                                                          \
  __builtin_amdgcn_global_load_lds(                                              \
      (const __attribute__((address_space(1))) void*)(gp),                       \
      (__attribute__((address_space(3))) void*)(lp), 16, 0, 0)

#define MFMA(a, b, c) __builtin_amdgcn_mfma_f32_16x16x32_bf16((a), (b), (c), 0, 0, 0)

// ---------------------------------------------------------------- fp32 -> bf16
__global__ __launch_bounds__(256) void cvt_bf16(const float* __restrict__ s,
                                                u16* __restrict__ d) {
  size_t i = (size_t)blockIdx.x * 256 + threadIdx.x;  // 8 elems/thread
  const float4* sp = (const float4*)s + i * 2;
  float4 a = sp[0], b = sp[1];
  s16x8 r;
  r[0] = f2bf(a.x); r[1] = f2bf(a.y); r[2] = f2bf(a.z); r[3] = f2bf(a.w);
  r[4] = f2bf(b.x); r[5] = f2bf(b.y); r[6] = f2bf(b.z); r[7] = f2bf(b.w);
  *(s16x8*)(d + i * 8) = r;
}

// 3 weight matrices in one launch (grid 1536 = 3*512)
__global__ __launch_bounds__(256) void cvt_w3(
    const float* __restrict__ a, const float* __restrict__ b,
    const float* __restrict__ c, u16* __restrict__ oa, u16* __restrict__ ob,
    u16* __restrict__ oc) {
  int bid = blockIdx.x;
  int which = bid >> 9, r = bid & 511;
  const float* s = (which == 0) ? a : (which == 1) ? b : c;
  u16* d = (which == 0) ? oa : (which == 1) ? ob : oc;
  size_t i = (size_t)r * 256 + threadIdx.x;
  const float4* sp = (const float4*)s + i * 2;
  float4 x = sp[0], y = sp[1];
  s16x8 v;
  v[0] = f2bf(x.x); v[1] = f2bf(x.y); v[2] = f2bf(x.z); v[3] = f2bf(x.w);
  v[4] = f2bf(y.x); v[5] = f2bf(y.y); v[6] = f2bf(y.z); v[7] = f2bf(y.w);
  *(s16x8*)(d + i * 8) = v;
}

// ------------------------------------------------------------------- QKV GEMM
__global__ __launch_bounds__(256) void qkv_gemm(
    const u16* __restrict__ Xb,
    const u16* __restrict__ Wqb, const u16* __restrict__ Wkb,
    const u16* __restrict__ Wvb,
    const float* __restrict__ bq, const float* __restrict__ bk,
    const float* __restrict__ bv,
    u16* __restrict__ Qo, u16* __restrict__ Ko, u16* __restrict__ Vto) {
  int bid0 = blockIdx.x;
  int bid  = (bid0 & 7) * 192 + (bid0 >> 3);  // XCD swizzle (1536 = 8*192)
  int which = bid >> 9;
  int rt = bid & 511;
  int mt = rt >> 3, ntl = rt & 7;
  const u16* W = (which == 0) ? Wqb : (which == 1) ? Wkb : Wvb;
  const float* bias = (which == 0) ? bq : (which == 1) ? bk : bv;

  __shared__ __align__(16) u16 As[128 * 32];
  __shared__ __align__(16) u16 Bs[128 * 32];

  int tid = threadIdx.x;
  int lane = tid & 63, wid = tid >> 6;
  int q16 = lane & 15, g = lane >> 4;
  int wr = wid >> 1, wc = wid & 1;

  int arow = tid >> 2;
  int ainner = (tid & 3) << 4;
  const char* Ag = (const char*)Xb + ((size_t)(mt * 128 + arow) * 1024) * 2 + ainner;
  const char* Bg = (const char*)W + ((size_t)(ntl * 128 + arow) * 1024) * 2 + ainner;
  char* Al = (char*)As + tid * 16;
  char* Bl = (char*)Bs + tid * 16;

  f32x4 acc[4][4] = {};

  for (int kb = 0; kb < 1024; kb += 32) {
    GLOAD16(Ag + kb * 2, Al);
    GLOAD16(Ag + kb * 2 + 64 * 2048, Al + 4096);
    GLOAD16(Bg + kb * 2, Bl);
    GLOAD16(Bg + kb * 2 + 64 * 2048, Bl + 4096);
    __syncthreads();
    s16x8 af[4], bf[4];
#pragma unroll
    for (int mi = 0; mi < 4; ++mi)
      af[mi] = *(const s16x8*)((const char*)As + (wr * 64 + mi * 16 + q16) * 64 + g * 16);
#pragma unroll
    for (int ni = 0; ni < 4; ++ni)
      bf[ni] = *(const s16x8*)((const char*)Bs + (wc * 64 + ni * 16 + q16) * 64 + g * 16);
#pragma unroll
    for (int mi = 0; mi < 4; ++mi)
#pragma unroll
      for (int ni = 0; ni < 4; ++ni)
        acc[mi][ni] = MFMA(af[mi], bf[ni], acc[mi][ni]);
    __syncthreads();
  }

  float qsc = (which == 0) ? (0.125f * LOG2E) : 1.0f;
  u16* Out = (which == 0) ? Qo : (which == 1) ? Ko : Vto;
#pragma unroll
  for (int ni = 0; ni < 4; ++ni) {
    int n = ntl * 128 + wc * 64 + ni * 16 + q16;
    float bvl = bias[n];
    int h = n >> 6, d = n & 63;
#pragma unroll
    for (int mi = 0; mi < 4; ++mi) {
      int m0 = mt * 128 + wr * 64 + mi * 16 + g * 4;
#pragma unroll
      for (int j = 0; j < 4; ++j) {
        int m = m0 + j;
        int bb = m >> 11, t = m & 2047;
        float v = (acc[mi][ni][j] + bvl) * qsc;
        size_t addr;
        if (which == 2) addr = ((size_t)(bb * 16 + h) * 64 + d) * 2048 + t;
        else            addr = ((size_t)(bb * 16 + h) * 2048 + t) * 64 + d;
        Out[addr] = f2bf(v);
      }
    }
  }
}

// ------------------------------------------------------------- flash attention
// grid 2048 = 64 bh * 32 q-tiles; 4 waves x 16 q-rows.
// Swapped QK^T: sA = MFMA(Kfrag, Qfrag) -> P[k][q], q = lane&15.
// K rows fed in permuted order kk = 32c + 8*(i>>2) + 4*t4 + (i&3) so lane-held P
// lands in B-fragment slot order (slot 8g + 4t4 + r <-> logical k 32c+8g+4t4+r).
// LDS swizzle f(row) = (row&7) ^ ((row>>1)&4), applied on the staging SOURCE
// address (global_load_lds dest must stay linear, m104/m173).
__global__ __launch_bounds__(256) void attn_fwd(
    const u16* __restrict__ Qw, const u16* __restrict__ Kw,
    const u16* __restrict__ Vtw, const float* __restrict__ maskp,
    float* __restrict__ out) {
  int bid0 = blockIdx.x;
  int bid = (bid0 & 7) * 256 + (bid0 >> 3);  // XCD swizzle: 8 whole bh per XCD
  int bh = bid >> 5, qt = bid & 31;
  int qb = qt << 6;
  int tid = threadIdx.x;
  int lane = tid & 63, wid = tid >> 6;
  int q16 = lane & 15, g = lane >> 4;

  __shared__ __align__(16) char Ks[2][8192];   // [k 64][128B] swizzled
  __shared__ __align__(16) char Vs[2][8192];   // V^T [d 64][128B k] swizzled
  __shared__ __align__(16) float maskl[2048];  // mask * log2e

  // Q fragment (B-operand layout): lane holds col q16, d-slots g*8+j
  size_t qrow = (size_t)bh * 2048 + qb + wid * 16 + q16;
  s16x8 qa0 = *(const s16x8*)(Qw + qrow * 64 + g * 8);
  s16x8 qa1 = *(const s16x8*)(Qw + qrow * 64 + 32 + g * 8);

  // staging: 16B/thread, rows srow and srow+32 (same swizzle: f depends on row&15 bits 0..3)
  int srow = tid >> 3;
  int sinner = (tid & 7) << 4;
  int fs = (srow & 7) ^ ((srow >> 1) & 4);
  int ssw = sinner ^ (fs << 4);
  const char* Kg = (const char*)Kw + ((size_t)bh * 2048 + srow) * 128 + ssw;
  const char* Vg = (const char*)Vtw + ((size_t)bh * 64 + srow) * 4096 + ssw;

  // mask row -> LDS, pre-scaled
  {
    const float* mrow = maskp + (size_t)(bh >> 4) * 2048;
    f32x4 a = *(const f32x4*)(mrow + tid * 4);
    f32x4 b = *(const f32x4*)(mrow + 1024 + tid * 4);
    *(f32x4*)(maskl + tid * 4) = a * LOG2E;
    *(f32x4*)(maskl + 1024 + tid * 4) = b * LOG2E;
  }

  // prologue: stage tile 0 -> buf 0
  GLOAD16(Kg, Ks[0] + tid * 16);
  GLOAD16(Kg + 4096, Ks[0] + tid * 16 + 4096);
  GLOAD16(Vg, Vs[0] + tid * 16);
  GLOAD16(Vg + 131072, Vs[0] + tid * 16 + 4096);
  __syncthreads();

  f32x4 o[4] = {};
  f32x4 lones = {};
  const s16x8 ones = {0x3F80, 0x3F80, 0x3F80, 0x3F80, 0x3F80, 0x3F80, 0x3F80, 0x3F80};

  int qcol = qb + wid * 16 + q16;
  int ntile = qt + 1;

  for (int kt = 0; kt < ntile; ++kt) {
    int cur = kt & 1;
    if (kt + 1 < ntile) {                       // stage next tile (other buffer)
      size_t kb2 = (size_t)(kt + 1) << 6;
      char* kd = Ks[cur ^ 1] + tid * 16;
      char* vd = Vs[cur ^ 1] + tid * 16;
      GLOAD16(Kg + kb2 * 128, kd);
      GLOAD16(Kg + kb2 * 128 + 4096, kd + 4096);
      GLOAD16(Vg + kb2 * 2, vd);
      GLOAD16(Vg + kb2 * 2 + 131072, vd + 4096);
      asm volatile("s_waitcnt vmcnt(4)" ::: "memory");  // current tile landed
    } else {
      asm volatile("s_waitcnt vmcnt(0)" ::: "memory");
    }
    __builtin_amdgcn_s_barrier();
    asm volatile("" ::: "memory");

    int kb = kt << 6;
    const char* ksb = Ks[cur];
    const char* vsb = Vs[cur];
    bool causal = (kt == qt);  // exactly one partially-masked tile per block

#pragma unroll
    for (int c = 0; c < 2; ++c) {
      f32x4 sA[2];
      __builtin_amdgcn_s_setprio(1);
#pragma unroll
      for (int t4 = 0; t4 < 2; ++t4) {
        int kk = 32 * c + ((q16 >> 2) << 3) + (t4 << 2) + (q16 & 3);
        int fk = (kk & 7) ^ ((kk >> 1) & 4);
        const char* krow = ksb + kk * 128;
        int in0 = (g * 16) ^ (fk << 4);
        s16x8 kf0 = *(const s16x8*)(krow + in0);
        s16x8 kf1 = *(const s16x8*)(krow + (in0 ^ 64));
        f32x4 sv = {0.f, 0.f, 0.f, 0.f};
        sv = MFMA(kf0, qa0, sv);
        sv = MFMA(kf1, qa1, sv);
        sA[t4] = sv;
      }
      __builtin_amdgcn_s_setprio(0);

      union { s16x8 v; unsigned u[4]; } pb;
#pragma unroll
      for (int t4 = 0; t4 < 2; ++t4) {
        f32x4 mv = *(const f32x4*)(maskl + kb + 32 * c + 8 * g + 4 * t4);
        float p0 = ex2(sA[t4][0] + mv[0]);
        float p1 = ex2(sA[t4][1] + mv[1]);
        float p2 = ex2(sA[t4][2] + mv[2]);
        float p3 = ex2(sA[t4][3] + mv[3]);
        if (causal) {
          int k0 = kb + 32 * c + 8 * g + 4 * t4;
          p0 = (k0 + 0 <= qcol) ? p0 : 0.f;
          p1 = (k0 + 1 <= qcol) ? p1 : 0.f;
          p2 = (k0 + 2 <= qcol) ? p2 : 0.f;
          p3 = (k0 + 3 <= qcol) ? p3 : 0.f;
        }
        pb.u[t4 * 2 + 0] = cvtpk(p0, p1);
        pb.u[t4 * 2 + 1] = cvtpk(p2, p3);
      }

      __builtin_amdgcn_s_setprio(1);
#pragma unroll
      for (int dt = 0; dt < 4; ++dt) {
        int d = dt * 16 + q16;
        int fv = (d & 7) ^ ((d >> 1) & 4);
        s16x8 vf = *(const s16x8*)(vsb + d * 128 + ((64 * c + 16 * g) ^ (fv << 4)));
        o[dt] = MFMA(vf, pb.v, o[dt]);
      }
      lones = MFMA(ones, pb.v, lones);  // l = sum_k P, every lane gets its q's sum
      __builtin_amdgcn_s_setprio(0);
    }
    __builtin_amdgcn_s_barrier();
  }

  float inv = rcp_(lones[0]);
  float* orow = out + ((size_t)bh * 2048 + qb + wid * 16 + q16) * 64 + g * 4;
#pragma unroll
  for (int dt = 0; dt < 4; ++dt)
    *(f32x4*)(orow + dt * 16) = o[dt] * inv;
}

// ------------------------------------------------------------------- launcher
extern "C" void kernel_launch(void* const* d_in, const int* in_sizes, int n_in,
                              void* d_out, int out_size, void* d_ws, size_t ws_size,
                              hipStream_t stream) {
  const float* hs   = (const float*)d_in[0];
  const float* mask = (const float*)d_in[1];
  const float* Wq   = (const float*)d_in[2];
  const float* bq   = (const float*)d_in[3];
  const float* Wk   = (const float*)d_in[4];
  const float* bk   = (const float*)d_in[5];
  const float* Wv   = (const float*)d_in[6];
  const float* bv   = (const float*)d_in[7];
  float* out = (float*)d_out;

  char* w = (char*)d_ws;
  u16* Xb  = (u16*)w; w += (size_t)8192 * 1024 * 2;
  u16* Wqb = (u16*)w; w += (size_t)1024 * 1024 * 2;
  u16* Wkb = (u16*)w; w += (size_t)1024 * 1024 * 2;
  u16* Wvb = (u16*)w; w += (size_t)1024 * 1024 * 2;
  u16* Qw  = (u16*)w; w += (size_t)8192 * 1024 * 2;
  u16* Kw  = (u16*)w; w += (size_t)8192 * 1024 * 2;
  u16* Vtw = (u16*)w; w += (size_t)8192 * 1024 * 2;

  cvt_bf16<<<4096, 256, 0, stream>>>(hs, Xb);
  cvt_w3<<<1536, 256, 0, stream>>>(Wq, Wk, Wv, Wqb, Wkb, Wvb);
  qkv_gemm<<<1536, 256, 0, stream>>>(Xb, Wqb, Wkb, Wvb, bq, bk, bv, Qw, Kw, Vtw);
  attn_fwd<<<2048, 256, 0, stream>>>(Qw, Kw, Vtw, mask, out);
}

// Round 3
// 176.015 us; speedup vs baseline: 1.5104x; 1.0367x over previous
//
#include <hip/hip_runtime.h>
#include <hip/hip_bf16.h>

// CausalSelfAttention: B=4 T=2048 H=1024 NH=16 HD=64, fp32 I/O, bf16 MFMA internal.
// cvt_all(X,W*)->bf16 ; fused QKV NT-GEMM: 256x128x64 tiles, 8 waves, 4-phase
// counted-vmcnt pipeline (T3+T4), XOR-swizzled LDS (T2), setprio (T5); writes
// Q(pre-scaled 0.125*log2e), K as [bh][t][d], V^T as [bh][d][t].
// flash attn: swapped QK^T (P[k][q] lane-local), no-max exp2 softmax, normalizer
// via ones-fragment MFMA, P in registers, dbuf K/V staging with vmcnt(4).

typedef float  f32x4 __attribute__((ext_vector_type(4)));
typedef short  s16x8 __attribute__((ext_vector_type(8)));
typedef unsigned short u16;

#define LOG2E 1.44269504088896340736f

__device__ __forceinline__ u16 f2bf(float f) {
  unsigned u = __float_as_uint(f);
  u += 0x7FFFu + ((u >> 16) & 1u);   // RNE (inputs finite)
  return (u16)(u >> 16);
}

__device__ __forceinline__ float ex2(float x) {
#if __has_builtin(__builtin_amdgcn_exp2f)
  return __builtin_amdgcn_exp2f(x);
#else
  return exp2f(x);
#endif
}
__device__ __forceinline__ float rcp_(float x) {
#if __has_builtin(__builtin_amdgcn_rcpf)
  return __builtin_amdgcn_rcpf(x);
#else
  return 1.0f / x;
#endif
}
__device__ __forceinline__ unsigned cvtpk(float lo, float hi) {
  unsigned r;
  asm("v_cvt_pk_bf16_f32 %0, %1, %2" : "=v"(r) : "v"(lo), "v"(hi));
  return r;
}
__device__ __forceinline__ void bar() {
  asm volatile("" ::: "memory");
  __builtin_amdgcn_s_barrier();
  asm volatile("" ::: "memory");
}

#define GLOAD16(gp, lp)                                                          \
  __builtin_amdgcn_global_load_lds(                                              \
      (const __attribute__((address_space(1))) void*)(gp),                       \
      (__attribute__((address_space(3))) void*)(lp), 16, 0, 0)

#define MFMA(a, b, c) __builtin_amdgcn_mfma_f32_16x16x32_bf16((a), (b), (c), 0, 0, 0)

// ------------------------------------------------- fp32 -> bf16 (all 4 tensors)
__global__ __launch_bounds__(256) void cvt_all(
    const float* __restrict__ hs, const float* __restrict__ wq,
    const float* __restrict__ wk, const float* __restrict__ wv,
    u16* __restrict__ xo, u16* __restrict__ qo, u16* __restrict__ ko,
    u16* __restrict__ vo) {
  int b = blockIdx.x;
  const float* s;
  u16* d;
  size_t i;
  if (b < 4096) { s = hs; d = xo; i = (size_t)b * 256 + threadIdx.x; }
  else {
    int w = (b - 4096) >> 9, r = (b - 4096) & 511;
    s = (w == 0) ? wq : (w == 1) ? wk : wv;
    d = (w == 0) ? qo : (w == 1) ? ko : vo;
    i = (size_t)r * 256 + threadIdx.x;
  }
  const float4* sp = (const float4*)s + i * 2;
  float4 a = sp[0], c = sp[1];
  s16x8 r8;
  r8[0] = f2bf(a.x); r8[1] = f2bf(a.y); r8[2] = f2bf(a.z); r8[3] = f2bf(a.w);
  r8[4] = f2bf(c.x); r8[5] = f2bf(c.y); r8[6] = f2bf(c.z); r8[7] = f2bf(c.w);
  *(s16x8*)(d + i * 8) = r8;
}

// ------------------------------------------------------------------- QKV GEMM
// 256x128 tile, BK=64, 8 waves (4 m-rows x 2 n-cols, 64x64 each).
// LDS 96KB: A dbuf 2x32KB @0, B dbuf 2x16KB @65536.
// Rows are 128B; involution swizzle slot^=(row&7) on staging SOURCE + frag reads.
// 4-phase/iter schedule; s_waitcnt vmcnt(2) at phases 2 and 4 only.
__global__ __launch_bounds__(512, 2) void qkv_gemm(
    const u16* __restrict__ Xb,
    const u16* __restrict__ Wqb, const u16* __restrict__ Wkb,
    const u16* __restrict__ Wvb,
    const float* __restrict__ bq, const float* __restrict__ bk,
    const float* __restrict__ bv,
    u16* __restrict__ Qo, u16* __restrict__ Ko, u16* __restrict__ Vto) {
  int bid0 = blockIdx.x;
  int bid  = (bid0 & 7) * 96 + (bid0 >> 3);  // XCD swizzle, 768 = 8*96 bijective
  int which = bid >> 8;                      // 0..2 : Q,K,V
  int rt = bid & 255;
  int mt = rt >> 3, nt = rt & 7;             // 32 m-tiles x 8 n-tiles
  const u16* W = (which == 0) ? Wqb : (which == 1) ? Wkb : Wvb;
  const float* bias = (which == 0) ? bq : (which == 1) ? bk : bv;

  __shared__ __align__(16) char lds[98304];

  int tid = threadIdx.x;
  int lane = tid & 63, wid = tid >> 6;
  int q16 = lane & 15, g = lane >> 4;
  int wr = wid >> 1, wc = wid & 1;

  // staging source (pre-swizzled): thread covers (row = c*64 + srow, slot)
  int srow = tid >> 3, sslot = tid & 7;
  int sw = (sslot ^ (srow & 7)) << 4;   // byte offset within 128B row
  const char* Asrc = (const char*)Xb + (size_t)(mt * 256 + srow) * 2048 + sw;
  const char* Bsrc = (const char*)W  + (size_t)(nt * 128 + srow) * 2048 + sw;

  // fragment read addressing
  int slot0 = (g ^ (q16 & 7)) << 4;

#define STAGE_A(tt, buf) do { size_t so = (size_t)(tt) * 128;                    \
    GLOAD16(Asrc + so,          lds + (buf) * 32768 + tid * 16);                 \
    GLOAD16(Asrc + so + 131072, lds + (buf) * 32768 + 8192 + tid * 16);          \
    GLOAD16(Asrc + so + 262144, lds + (buf) * 32768 + 16384 + tid * 16);         \
    GLOAD16(Asrc + so + 393216, lds + (buf) * 32768 + 24576 + tid * 16); } while (0)

#define STAGE_B(tt, buf) do { size_t so = (size_t)(tt) * 128;                    \
    GLOAD16(Bsrc + so,          lds + 65536 + (buf) * 16384 + tid * 16);         \
    GLOAD16(Bsrc + so + 131072, lds + 65536 + (buf) * 16384 + 8192 + tid * 16); } while (0)

#define LDA(FA, buf, mp) do {                                                    \
    const char* p_ = lds + (buf) * 32768 + (wr * 64 + (mp) * 32 + q16) * 128;    \
    FA[0] = *(const s16x8*)(p_ + slot0);                                         \
    FA[1] = *(const s16x8*)(p_ + (slot0 ^ 64));                                  \
    FA[2] = *(const s16x8*)(p_ + 2048 + slot0);                                  \
    FA[3] = *(const s16x8*)(p_ + 2048 + (slot0 ^ 64)); } while (0)

#define LDB(FB, buf) do {                                                        \
    const char* p_ = lds + 65536 + (buf) * 16384 + (wc * 64 + q16) * 128;        \
    FB[0] = *(const s16x8*)(p_ + slot0);                                         \
    FB[1] = *(const s16x8*)(p_ + (slot0 ^ 64));                                  \
    FB[2] = *(const s16x8*)(p_ + 2048 + slot0);                                  \
    FB[3] = *(const s16x8*)(p_ + 2048 + (slot0 ^ 64));                           \
    FB[4] = *(const s16x8*)(p_ + 4096 + slot0);                                  \
    FB[5] = *(const s16x8*)(p_ + 4096 + (slot0 ^ 64));                           \
    FB[6] = *(const s16x8*)(p_ + 6144 + slot0);                                  \
    FB[7] = *(const s16x8*)(p_ + 6144 + (slot0 ^ 64)); } while (0)

#define MM16(mlo, FA, FB) do {                                                   \
    __builtin_amdgcn_s_setprio(1);                                               \
    _Pragma("unroll")                                                            \
    for (int n_ = 0; n_ < 4; ++n_) {                                             \
      acc[(mlo)][n_]     = MFMA(FA[0], FB[2 * n_],     acc[(mlo)][n_]);          \
      acc[(mlo)][n_]     = MFMA(FA[1], FB[2 * n_ + 1], acc[(mlo)][n_]);          \
      acc[(mlo) + 1][n_] = MFMA(FA[2], FB[2 * n_],     acc[(mlo) + 1][n_]);      \
      acc[(mlo) + 1][n_] = MFMA(FA[3], FB[2 * n_ + 1], acc[(mlo) + 1][n_]);      \
    }                                                                            \
    __builtin_amdgcn_s_setprio(0); } while (0)

#define VM2 asm volatile("s_waitcnt vmcnt(2)" ::: "memory")

  // prologue: A(0),B(0) -> buf0 ; B(1) -> buf1 ; leave B(1) in flight
  STAGE_A(0, 0);
  STAGE_B(0, 0);
  STAGE_B(1, 1);
  VM2;
  bar();

  f32x4 acc[4][4] = {};
  s16x8 fA[4], fB[8];

#pragma unroll 1
  for (int i = 0; i < 8; ++i) {
    int t0 = 2 * i;
    // Phase 1: tile 2i (buf0), m-reps 0-1
    LDA(fA, 0, 0);
    LDB(fB, 0);
    STAGE_A((t0 + 1) & 15, 1);
    bar();
    MM16(0, fA, fB);
    bar();
    // Phase 2: tile 2i (buf0), m-reps 2-3
    LDA(fA, 0, 1);
    STAGE_B((t0 + 2) & 15, 0);
    VM2;
    bar();
    MM16(2, fA, fB);
    bar();
    // Phase 3: tile 2i+1 (buf1), m-reps 0-1
    LDA(fA, 1, 0);
    LDB(fB, 1);
    STAGE_A((t0 + 2) & 15, 0);
    bar();
    MM16(0, fA, fB);
    bar();
    // Phase 4: tile 2i+1 (buf1), m-reps 2-3
    LDA(fA, 1, 1);
    STAGE_B((t0 + 3) & 15, 1);
    VM2;
    bar();
    MM16(2, fA, fB);
    bar();
  }

  // epilogue
  float qsc = (which == 0) ? (0.125f * LOG2E) : 1.0f;
  u16* Out = (which == 0) ? Qo : (which == 1) ? Ko : Vto;
#pragma unroll
  for (int n = 0; n < 4; ++n) {
    int n_g = nt * 128 + wc * 64 + n * 16 + q16;
    float bvl = bias[n_g];
    int h = n_g >> 6, d = n_g & 63;
#pragma unroll
    for (int m = 0; m < 4; ++m) {
      int row0 = mt * 256 + wr * 64 + m * 16 + g * 4;
#pragma unroll
      for (int j = 0; j < 4; ++j) {
        int mrow = row0 + j;
        int bb = mrow >> 11, t = mrow & 2047;
        float v = (acc[m][n][j] + bvl) * qsc;
        size_t addr;
        if (which == 2) addr = ((size_t)(bb * 16 + h) * 64 + d) * 2048 + t;
        else            addr = ((size_t)(bb * 16 + h) * 2048 + t) * 64 + d;
        Out[addr] = f2bf(v);
      }
    }
  }
#undef STAGE_A
#undef STAGE_B
#undef LDA
#undef LDB
#undef MM16
#undef VM2
}

// ------------------------------------------------------------- flash attention
// grid 2048 = 64 bh * 32 q-tiles; 4 waves x 16 q-rows. Swapped QK^T; P in regs;
// normalizer via ones-fragment MFMA; dbuf K/V with counted vmcnt(4).
__global__ __launch_bounds__(256) void attn_fwd(
    const u16* __restrict__ Qw, const u16* __restrict__ Kw,
    const u16* __restrict__ Vtw, const float* __restrict__ maskp,
    float* __restrict__ out) {
  int bid0 = blockIdx.x;
  int bid = (bid0 & 7) * 256 + (bid0 >> 3);  // XCD swizzle: 8 whole bh per XCD
  int bh = bid >> 5, qt = bid & 31;
  int qb = qt << 6;
  int tid = threadIdx.x;
  int lane = tid & 63, wid = tid >> 6;
  int q16 = lane & 15, g = lane >> 4;

  __shared__ __align__(16) char Ks[2][8192];   // [k 64][128B] swizzled
  __shared__ __align__(16) char Vs[2][8192];   // V^T [d 64][128B k] swizzled
  __shared__ __align__(16) float maskl[2048];  // mask * log2e

  size_t qrow = (size_t)bh * 2048 + qb + wid * 16 + q16;
  s16x8 qa0 = *(const s16x8*)(Qw + qrow * 64 + g * 8);
  s16x8 qa1 = *(const s16x8*)(Qw + qrow * 64 + 32 + g * 8);

  int srow = tid >> 3;
  int sinner = (tid & 7) << 4;
  int fs = (srow & 7) ^ ((srow >> 1) & 4);
  int ssw = sinner ^ (fs << 4);
  const char* Kg = (const char*)Kw + ((size_t)bh * 2048 + srow) * 128 + ssw;
  const char* Vg = (const char*)Vtw + ((size_t)bh * 64 + srow) * 4096 + ssw;

  {
    const float* mrow = maskp + (size_t)(bh >> 4) * 2048;
    f32x4 a = *(const f32x4*)(mrow + tid * 4);
    f32x4 b = *(const f32x4*)(mrow + 1024 + tid * 4);
    *(f32x4*)(maskl + tid * 4) = a * LOG2E;
    *(f32x4*)(maskl + 1024 + tid * 4) = b * LOG2E;
  }

  GLOAD16(Kg, Ks[0] + tid * 16);
  GLOAD16(Kg + 4096, Ks[0] + tid * 16 + 4096);
  GLOAD16(Vg, Vs[0] + tid * 16);
  GLOAD16(Vg + 131072, Vs[0] + tid * 16 + 4096);
  __syncthreads();

  f32x4 o[4] = {};
  f32x4 lones = {};
  const s16x8 ones = {0x3F80, 0x3F80, 0x3F80, 0x3F80, 0x3F80, 0x3F80, 0x3F80, 0x3F80};

  int qcol = qb + wid * 16 + q16;
  int ntile = qt + 1;

  for (int kt = 0; kt < ntile; ++kt) {
    int cur = kt & 1;
    if (kt + 1 < ntile) {
      size_t kb2 = (size_t)(kt + 1) << 6;
      char* kd = Ks[cur ^ 1] + tid * 16;
      char* vd = Vs[cur ^ 1] + tid * 16;
      GLOAD16(Kg + kb2 * 128, kd);
      GLOAD16(Kg + kb2 * 128 + 4096, kd + 4096);
      GLOAD16(Vg + kb2 * 2, vd);
      GLOAD16(Vg + kb2 * 2 + 131072, vd + 4096);
      asm volatile("s_waitcnt vmcnt(4)" ::: "memory");
    } else {
      asm volatile("s_waitcnt vmcnt(0)" ::: "memory");
    }
    __builtin_amdgcn_s_barrier();
    asm volatile("" ::: "memory");

    int kb = kt << 6;
    const char* ksb = Ks[cur];
    const char* vsb = Vs[cur];
    bool causal = (kt == qt);

#pragma unroll
    for (int c = 0; c < 2; ++c) {
      f32x4 sA[2];
      __builtin_amdgcn_s_setprio(1);
#pragma unroll
      for (int t4 = 0; t4 < 2; ++t4) {
        int kk = 32 * c + ((q16 >> 2) << 3) + (t4 << 2) + (q16 & 3);
        int fk = (kk & 7) ^ ((kk >> 1) & 4);
        const char* krow = ksb + kk * 128;
        int in0 = (g * 16) ^ (fk << 4);
        s16x8 kf0 = *(const s16x8*)(krow + in0);
        s16x8 kf1 = *(const s16x8*)(krow + (in0 ^ 64));
        f32x4 sv = {0.f, 0.f, 0.f, 0.f};
        sv = MFMA(kf0, qa0, sv);
        sv = MFMA(kf1, qa1, sv);
        sA[t4] = sv;
      }
      __builtin_amdgcn_s_setprio(0);

      union { s16x8 v; unsigned u[4]; } pb;
#pragma unroll
      for (int t4 = 0; t4 < 2; ++t4) {
        f32x4 mv = *(const f32x4*)(maskl + kb + 32 * c + 8 * g + 4 * t4);
        float p0 = ex2(sA[t4][0] + mv[0]);
        float p1 = ex2(sA[t4][1] + mv[1]);
        float p2 = ex2(sA[t4][2] + mv[2]);
        float p3 = ex2(sA[t4][3] + mv[3]);
        if (causal) {
          int k0 = kb + 32 * c + 8 * g + 4 * t4;
          p0 = (k0 + 0 <= qcol) ? p0 : 0.f;
          p1 = (k0 + 1 <= qcol) ? p1 : 0.f;
          p2 = (k0 + 2 <= qcol) ? p2 : 0.f;
          p3 = (k0 + 3 <= qcol) ? p3 : 0.f;
        }
        pb.u[t4 * 2 + 0] = cvtpk(p0, p1);
        pb.u[t4 * 2 + 1] = cvtpk(p2, p3);
      }

      __builtin_amdgcn_s_setprio(1);
#pragma unroll
      for (int dt = 0; dt < 4; ++dt) {
        int d = dt * 16 + q16;
        int fv = (d & 7) ^ ((d >> 1) & 4);
        s16x8 vf = *(const s16x8*)(vsb + d * 128 + ((64 * c + 16 * g) ^ (fv << 4)));
        o[dt] = MFMA(vf, pb.v, o[dt]);
      }
      lones = MFMA(ones, pb.v, lones);
      __builtin_amdgcn_s_setprio(0);
    }
    __builtin_amdgcn_s_barrier();
  }

  float inv = rcp_(lones[0]);
  float* orow = out + ((size_t)bh * 2048 + qb + wid * 16 + q16) * 64 + g * 4;
#pragma unroll
  for (int dt = 0; dt < 4; ++dt)
    *(f32x4*)(orow + dt * 16) = o[dt] * inv;
}

// ------------------------------------------------------------------- launcher
extern "C" void kernel_launch(void* const* d_in, const int* in_sizes, int n_in,
                              void* d_out, int out_size, void* d_ws, size_t ws_size,
                              hipStream_t stream) {
  const float* hs   = (const float*)d_in[0];
  const float* mask = (const float*)d_in[1];
  const float* Wq   = (const float*)d_in[2];
  const float* bq   = (const float*)d_in[3];
  const float* Wk   = (const float*)d_in[4];
  const float* bk   = (const float*)d_in[5];
  const float* Wv   = (const float*)d_in[6];
  const float* bv   = (const float*)d_in[7];
  float* out = (float*)d_out;

  char* w = (char*)d_ws;
  u16* Xb  = (u16*)w; w += (size_t)8192 * 1024 * 2;
  u16* Wqb = (u16*)w; w += (size_t)1024 * 1024 * 2;
  u16* Wkb = (u16*)w; w += (size_t)1024 * 1024 * 2;
  u16* Wvb = (u16*)w; w += (size_t)1024 * 1024 * 2;
  u16* Qw  = (u16*)w; w += (size_t)8192 * 1024 * 2;
  u16* Kw  = (u16*)w; w += (size_t)8192 * 1024 * 2;
  u16* Vtw = (u16*)w; w += (size_t)8192 * 1024 * 2;

  cvt_all<<<5632, 256, 0, stream>>>(hs, Wq, Wk, Wv, Xb, Wqb, Wkb, Wvb);
  qkv_gemm<<<768, 512, 0, stream>>>(Xb, Wqb, Wkb, Wvb, bq, bk, bv, Qw, Kw, Vtw);
  attn_fwd<<<2048, 256, 0, stream>>>(Qw, Kw, Vtw, mask, out);
}